// Round 1
// baseline (1366.706 us; speedup 1.0000x reference)
//
#include <hip/hip_runtime.h>
#include <math.h>

namespace {

constexpr int B = 4, S = 2048, D = 1024, H = 64, NH = 16;
constexpr int BS = B * S;          // 8192 rows total
constexpr float SCALE = 0.125f;    // 1/sqrt(H)

// ---------------------------------------------------------------------------
// Wproj_eff[h][e] = sum_t Wproj[t*64+h][e]   (all 16 heads identical -> fold)
// ---------------------------------------------------------------------------
__global__ __launch_bounds__(256) void fold_wproj_kernel(const float* __restrict__ Wproj,
                                                         float* __restrict__ Wpe) {
    const int idx = blockIdx.x * 256 + threadIdx.x;   // 0..65535
    const int e = idx & (D - 1);
    const int h = idx >> 10;
    float s = 0.f;
#pragma unroll
    for (int t = 0; t < NH; ++t) s += Wproj[(t * H + h) * D + e];
    Wpe[h * D + e] = s;
}

// ---------------------------------------------------------------------------
// q/k/v = x @ W{q,k,v}.  Block = 192 threads (3 waves; wave m does matrix m),
// 32 rows per block, x chunk staged in LDS, per-thread 32-row register tile.
// LDS reads are wave-uniform float4 broadcasts (cheap).
// ---------------------------------------------------------------------------
__global__ __launch_bounds__(192) void qkv_kernel(const float* __restrict__ x,
                                                  const float* __restrict__ Wq,
                                                  const float* __restrict__ Wk,
                                                  const float* __restrict__ Wv,
                                                  float* __restrict__ qo,
                                                  float* __restrict__ ko,
                                                  float* __restrict__ vo) {
    __shared__ float xs[32 * 64];
    const int tid = threadIdx.x;
    const int row0 = blockIdx.x * 32;
    const int h = tid & 63;
    const int m = tid >> 6;  // 0=q, 1=k, 2=v (wave-uniform)
    const float* __restrict__ W = (m == 0) ? Wq : (m == 1) ? Wk : Wv;

    float acc[32];
#pragma unroll
    for (int r = 0; r < 32; ++r) acc[r] = 0.f;

    for (int d0 = 0; d0 < D; d0 += 64) {
        __syncthreads();
        for (int idx = tid; idx < 32 * 64; idx += 192) {
            const int r = idx >> 6, dc = idx & 63;
            xs[idx] = x[(row0 + r) * D + d0 + dc];
        }
        __syncthreads();
#pragma unroll 4
        for (int dc4 = 0; dc4 < 16; ++dc4) {
            const float w0 = W[(d0 + dc4 * 4 + 0) * H + h];
            const float w1 = W[(d0 + dc4 * 4 + 1) * H + h];
            const float w2 = W[(d0 + dc4 * 4 + 2) * H + h];
            const float w3 = W[(d0 + dc4 * 4 + 3) * H + h];
#pragma unroll
            for (int r = 0; r < 32; ++r) {
                const float4 xv = *reinterpret_cast<const float4*>(&xs[r * 64 + dc4 * 4]);
                acc[r] = fmaf(xv.x, w0, acc[r]);
                acc[r] = fmaf(xv.y, w1, acc[r]);
                acc[r] = fmaf(xv.z, w2, acc[r]);
                acc[r] = fmaf(xv.w, w3, acc[r]);
            }
        }
    }
    float* __restrict__ out = (m == 0) ? qo : (m == 1) ? ko : vo;
#pragma unroll
    for (int r = 0; r < 32; ++r) out[(row0 + r) * H + h] = acc[r];
}

// ---------------------------------------------------------------------------
// Causal flash attention, one wave per query row (lane = head-dim element).
// Online softmax; k/v per batch = 1 MB -> L2 resident.
// ---------------------------------------------------------------------------
__global__ __launch_bounds__(256) void attn_kernel(const float* __restrict__ q,
                                                   const float* __restrict__ k,
                                                   const float* __restrict__ v,
                                                   float* __restrict__ ctx) {
    const int lane = threadIdx.x & 63;
    const int row = blockIdx.x * 4 + (threadIdx.x >> 6);
    const int b = row >> 11;           // row / S
    const int qi = row & (S - 1);      // row % S
    const float qv = q[row * H + lane] * SCALE;
    const float* __restrict__ kb = k + b * S * H;
    const float* __restrict__ vb = v + b * S * H;

    float m = -1e30f, l = 0.f, o = 0.f;
    for (int j = 0; j <= qi; ++j) {
        float prod = qv * kb[j * H + lane];
#pragma unroll
        for (int off = 32; off > 0; off >>= 1) prod += __shfl_xor(prod, off, 64);
        const float s = prod;                 // wave-uniform score
        const float mn = fmaxf(m, s);
        const float corr = __expf(m - mn);
        const float p = __expf(s - mn);
        l = l * corr + p;
        o = o * corr + p * vb[j * H + lane];
        m = mn;
    }
    ctx[row * H + lane] = o / l;
}

// ---------------------------------------------------------------------------
// out = ctx @ Wproj_eff + bproj.  Each thread owns one output column e and
// keeps Wpe[:,e] (64 floats) in registers; ctx rows staged in LDS (broadcast).
// Grid: (D/256) x (BS/64).
// ---------------------------------------------------------------------------
__global__ __launch_bounds__(256) void proj_kernel(const float* __restrict__ ctx,
                                                   const float* __restrict__ Wpe,
                                                   const float* __restrict__ bias,
                                                   float* __restrict__ out) {
    __shared__ float cs[64 * 64];
    const int tid = threadIdx.x;
    const int e = blockIdx.x * 256 + tid;
    const int row0 = blockIdx.y * 64;

    float w[64];
#pragma unroll
    for (int h = 0; h < 64; ++h) w[h] = Wpe[h * D + e];
    const float bb = bias[e];

    for (int idx = tid; idx < 64 * 64; idx += 256) cs[idx] = ctx[row0 * H + idx];
    __syncthreads();

    for (int r = 0; r < 64; ++r) {
        float acc = bb;
#pragma unroll
        for (int h4 = 0; h4 < 16; ++h4) {
            const float4 c = *reinterpret_cast<const float4*>(&cs[r * 64 + h4 * 4]);
            acc = fmaf(c.x, w[h4 * 4 + 0], acc);
            acc = fmaf(c.y, w[h4 * 4 + 1], acc);
            acc = fmaf(c.z, w[h4 * 4 + 2], acc);
            acc = fmaf(c.w, w[h4 * 4 + 3], acc);
        }
        out[(row0 + r) * D + e] = acc;
    }
}

}  // namespace

extern "C" void kernel_launch(void* const* d_in, const int* in_sizes, int n_in,
                              void* d_out, int out_size, void* d_ws, size_t ws_size,
                              hipStream_t stream) {
    const float* x     = (const float*)d_in[0];
    const float* Wq    = (const float*)d_in[1];
    const float* Wk    = (const float*)d_in[2];
    const float* Wv    = (const float*)d_in[3];
    const float* Wproj = (const float*)d_in[4];
    const float* bproj = (const float*)d_in[5];
    float* out = (float*)d_out;

    float* ws  = (float*)d_ws;
    float* q   = ws;                 // BS*H
    float* k   = q + BS * H;         // BS*H
    float* v   = k + BS * H;         // BS*H
    float* ctx = v + BS * H;         // BS*H
    float* Wpe = ctx + BS * H;       // H*D
    // total: 4*524288 + 65536 floats = 8.65 MB of workspace

    hipLaunchKernelGGL(fold_wproj_kernel, dim3((H * D) / 256), dim3(256), 0, stream, Wproj, Wpe);
    hipLaunchKernelGGL(qkv_kernel, dim3(BS / 32), dim3(192), 0, stream, x, Wq, Wk, Wv, q, k, v);
    hipLaunchKernelGGL(attn_kernel, dim3(BS / 4), dim3(256), 0, stream, q, k, v, ctx);
    hipLaunchKernelGGL(proj_kernel, dim3(D / 256, BS / 64), dim3(256), 0, stream, ctx, Wpe, bproj, out);
}

// Round 2
// 468.727 us; speedup vs baseline: 2.9158x; 2.9158x over previous
//
#include <hip/hip_runtime.h>
#include <math.h>

namespace {

constexpr int B = 4, S = 2048, D = 1024, H = 64, NH = 16;
constexpr int BS = B * S;          // 8192 rows total
constexpr float SCALE = 0.125f;    // 1/sqrt(H)

// ---------------------------------------------------------------------------
// Wproj_eff[h][e] = sum_t Wproj[t*64+h][e]   (all 16 heads identical -> fold)
// ---------------------------------------------------------------------------
__global__ __launch_bounds__(256) void fold_wproj_kernel(const float* __restrict__ Wproj,
                                                         float* __restrict__ Wpe) {
    const int idx = blockIdx.x * 256 + threadIdx.x;   // 0..65535
    const int e = idx & (D - 1);
    const int h = idx >> 10;
    float s = 0.f;
#pragma unroll
    for (int t = 0; t < NH; ++t) s += Wproj[(t * H + h) * D + e];
    Wpe[h * D + e] = s;
}

// ---------------------------------------------------------------------------
// q/k/v = x @ W{q,k,v}.  Block = 192 threads (3 waves; wave m does matrix m),
// 32 rows per block, x chunk staged in LDS, per-thread 32-row register tile.
// ---------------------------------------------------------------------------
__global__ __launch_bounds__(192) void qkv_kernel(const float* __restrict__ x,
                                                  const float* __restrict__ Wq,
                                                  const float* __restrict__ Wk,
                                                  const float* __restrict__ Wv,
                                                  float* __restrict__ qo,
                                                  float* __restrict__ ko,
                                                  float* __restrict__ vo) {
    __shared__ float xs[32 * 64];
    const int tid = threadIdx.x;
    const int row0 = blockIdx.x * 32;
    const int h = tid & 63;
    const int m = tid >> 6;  // 0=q, 1=k, 2=v (wave-uniform)
    const float* __restrict__ W = (m == 0) ? Wq : (m == 1) ? Wk : Wv;

    float acc[32];
#pragma unroll
    for (int r = 0; r < 32; ++r) acc[r] = 0.f;

    for (int d0 = 0; d0 < D; d0 += 64) {
        __syncthreads();
        for (int idx = tid; idx < 32 * 64; idx += 192) {
            const int r = idx >> 6, dc = idx & 63;
            xs[idx] = x[(row0 + r) * D + d0 + dc];
        }
        __syncthreads();
#pragma unroll 4
        for (int dc4 = 0; dc4 < 16; ++dc4) {
            const float w0 = W[(d0 + dc4 * 4 + 0) * H + h];
            const float w1 = W[(d0 + dc4 * 4 + 1) * H + h];
            const float w2 = W[(d0 + dc4 * 4 + 2) * H + h];
            const float w3 = W[(d0 + dc4 * 4 + 3) * H + h];
#pragma unroll
            for (int r = 0; r < 32; ++r) {
                const float4 xv = *reinterpret_cast<const float4*>(&xs[r * 64 + dc4 * 4]);
                acc[r] = fmaf(xv.x, w0, acc[r]);
                acc[r] = fmaf(xv.y, w1, acc[r]);
                acc[r] = fmaf(xv.z, w2, acc[r]);
                acc[r] = fmaf(xv.w, w3, acc[r]);
            }
        }
    }
    float* __restrict__ out = (m == 0) ? qo : (m == 1) ? ko : vo;
#pragma unroll
    for (int r = 0; r < 32; ++r) out[(row0 + r) * H + h] = acc[r];
}

// ---------------------------------------------------------------------------
// Tile-parallel causal flash attention.
// Block = 256 thr (4 waves). QB=16 query rows/block, wave owns QW=4 rows.
// Key tiles of KT=64 staged in LDS (k XOR-swizzled for conflict-free b128
// row reads; v linear). Score phase: lane owns a key (64 keys parallel).
// PV phase: lane owns an h; p transposed through per-wave LDS buffer.
// ---------------------------------------------------------------------------
constexpr int QB = 16;
constexpr int QW = 4;
constexpr int KT = 64;

__global__ __launch_bounds__(256) void attn_kernel(const float* __restrict__ q,
                                                   const float* __restrict__ k,
                                                   const float* __restrict__ v,
                                                   float* __restrict__ ctx) {
    __shared__ float ks[KT * H];       // swizzled k tile
    __shared__ float vs[KT * H];       // linear v tile
    __shared__ float qs[QB * H];       // scaled q rows
    __shared__ float ps[4][QW][KT];    // per-wave p scratch

    const int tid = threadIdx.x;
    const int lane = tid & 63;
    const int wave = tid >> 6;
    const int bid = blockIdx.x;
    const int b = bid & 3;             // batch fast -> complementary tile counts pair up
    const int q0 = (bid >> 2) * QB;

    const float* __restrict__ kb = k + b * S * H;
    const float* __restrict__ vb = v + b * S * H;

    // stage q (pre-scaled): 16 rows * 64 = 256 float4, one per thread
    {
        const float4* qg = reinterpret_cast<const float4*>(q + (b * S + q0) * H);
        float4 t = qg[tid];
        t.x *= SCALE; t.y *= SCALE; t.z *= SCALE; t.w *= SCALE;
        reinterpret_cast<float4*>(qs)[tid] = t;
    }

    float o[QW], l[QW], m[QW];
#pragma unroll
    for (int r = 0; r < QW; ++r) { o[r] = 0.f; l[r] = 0.f; m[r] = -1e30f; }

    const int qi_base = q0 + wave * QW;            // wave's first row (within batch)
    const int nt = (q0 + QB + KT - 1) / KT;

    for (int t = 0; t < nt; ++t) {
        const int kt0 = t * KT;
        __syncthreads();   // protects qs (iter 0) and ks/vs from previous iter readers
        {
            const float4* kg = reinterpret_cast<const float4*>(kb + kt0 * H);
            const float4* vg = reinterpret_cast<const float4*>(vb + kt0 * H);
            float4* ks4 = reinterpret_cast<float4*>(ks);
            float4* vs4 = reinterpret_cast<float4*>(vs);
#pragma unroll
            for (int it = 0; it < 4; ++it) {
                const int i = tid + it * 256;      // float4 idx 0..1023
                const int j = i >> 4, c4 = i & 15;
                ks4[j * 16 + (c4 ^ (j & 7))] = kg[i];
                vs4[i] = vg[i];
            }
        }
        __syncthreads();

        // ---- scores: lane owns key kt0+lane ----
        float4 kr[16];
        {
            const float4* ks4 = reinterpret_cast<const float4*>(ks);
#pragma unroll
            for (int c4 = 0; c4 < 16; ++c4)
                kr[c4] = ks4[lane * 16 + (c4 ^ (lane & 7))];
        }
        const int kj = kt0 + lane;
        float s[QW];
#pragma unroll
        for (int rr = 0; rr < QW; ++rr) {
            const float4* q4 = reinterpret_cast<const float4*>(qs + (wave * QW + rr) * H);
            float acc = 0.f;
#pragma unroll
            for (int c4 = 0; c4 < 16; ++c4) {
                const float4 qv = q4[c4];   // uniform -> LDS broadcast
                acc = fmaf(qv.x, kr[c4].x, acc);
                acc = fmaf(qv.y, kr[c4].y, acc);
                acc = fmaf(qv.z, kr[c4].z, acc);
                acc = fmaf(qv.w, kr[c4].w, acc);
            }
            s[rr] = acc;
        }

        // ---- online softmax, one reduce pair per 64-key tile per row ----
#pragma unroll
        for (int rr = 0; rr < QW; ++rr) {
            const int qi = qi_base + rr;
            const float msk = (kj <= qi) ? 1.f : 0.f;
            float sv = (kj <= qi) ? s[rr] : -1e30f;
            float smax = sv;
#pragma unroll
            for (int off = 32; off > 0; off >>= 1)
                smax = fmaxf(smax, __shfl_xor(smax, off, 64));
            const float mn = fmaxf(m[rr], smax);
            const float p = __expf(sv - mn) * msk;
            float psum = p;
#pragma unroll
            for (int off = 32; off > 0; off >>= 1)
                psum += __shfl_xor(psum, off, 64);
            const float corr = __expf(m[rr] - mn);
            l[rr] = l[rr] * corr + psum;
            o[rr] *= corr;
            m[rr] = mn;
            ps[wave][rr][lane] = p;      // own slice; same-wave read below (lgkmcnt)
        }

        // ---- PV: lane owns h = lane; v column reads conflict-free ----
#pragma unroll 4
        for (int j4 = 0; j4 < 16; ++j4) {
            const float v0 = vs[(j4 * 4 + 0) * H + lane];
            const float v1 = vs[(j4 * 4 + 1) * H + lane];
            const float v2 = vs[(j4 * 4 + 2) * H + lane];
            const float v3 = vs[(j4 * 4 + 3) * H + lane];
#pragma unroll
            for (int rr = 0; rr < QW; ++rr) {
                const float4 pp = *reinterpret_cast<const float4*>(&ps[wave][rr][j4 * 4]);
                o[rr] = fmaf(pp.x, v0, o[rr]);
                o[rr] = fmaf(pp.y, v1, o[rr]);
                o[rr] = fmaf(pp.z, v2, o[rr]);
                o[rr] = fmaf(pp.w, v3, o[rr]);
            }
        }
    }

#pragma unroll
    for (int rr = 0; rr < QW; ++rr) {
        const int row = b * S + qi_base + rr;
        ctx[row * H + lane] = o[rr] / l[rr];
    }
}

// ---------------------------------------------------------------------------
// out = ctx @ Wproj_eff + bproj.
// ---------------------------------------------------------------------------
__global__ __launch_bounds__(256) void proj_kernel(const float* __restrict__ ctx,
                                                   const float* __restrict__ Wpe,
                                                   const float* __restrict__ bias,
                                                   float* __restrict__ out) {
    __shared__ float cs[64 * 64];
    const int tid = threadIdx.x;
    const int e = blockIdx.x * 256 + tid;
    const int row0 = blockIdx.y * 64;

    float w[64];
#pragma unroll
    for (int h = 0; h < 64; ++h) w[h] = Wpe[h * D + e];
    const float bb = bias[e];

    for (int idx = tid; idx < 64 * 64; idx += 256) cs[idx] = ctx[row0 * H + idx];
    __syncthreads();

    for (int r = 0; r < 64; ++r) {
        float acc = bb;
#pragma unroll
        for (int h4 = 0; h4 < 16; ++h4) {
            const float4 c = *reinterpret_cast<const float4*>(&cs[r * 64 + h4 * 4]);
            acc = fmaf(c.x, w[h4 * 4 + 0], acc);
            acc = fmaf(c.y, w[h4 * 4 + 1], acc);
            acc = fmaf(c.z, w[h4 * 4 + 2], acc);
            acc = fmaf(c.w, w[h4 * 4 + 3], acc);
        }
        out[(row0 + r) * D + e] = acc;
    }
}

}  // namespace

extern "C" void kernel_launch(void* const* d_in, const int* in_sizes, int n_in,
                              void* d_out, int out_size, void* d_ws, size_t ws_size,
                              hipStream_t stream) {
    const float* x     = (const float*)d_in[0];
    const float* Wq    = (const float*)d_in[1];
    const float* Wk    = (const float*)d_in[2];
    const float* Wv    = (const float*)d_in[3];
    const float* Wproj = (const float*)d_in[4];
    const float* bproj = (const float*)d_in[5];
    float* out = (float*)d_out;

    float* ws  = (float*)d_ws;
    float* q   = ws;                 // BS*H
    float* k   = q + BS * H;         // BS*H
    float* v   = k + BS * H;         // BS*H
    float* ctx = v + BS * H;         // BS*H
    float* Wpe = ctx + BS * H;       // H*D

    hipLaunchKernelGGL(fold_wproj_kernel, dim3((H * D) / 256), dim3(256), 0, stream, Wproj, Wpe);
    hipLaunchKernelGGL(qkv_kernel, dim3(BS / 32), dim3(192), 0, stream, x, Wq, Wk, Wv, q, k, v);
    hipLaunchKernelGGL(attn_kernel, dim3((S / QB) * B), dim3(256), 0, stream, q, k, v, ctx);
    hipLaunchKernelGGL(proj_kernel, dim3(D / 256, BS / 64), dim3(256), 0, stream, ctx, Wpe, bproj, out);
}

// Round 3
// 284.427 us; speedup vs baseline: 4.8051x; 1.6480x over previous
//
#include <hip/hip_runtime.h>
#include <math.h>

namespace {

constexpr int B = 4, S = 2048, D = 1024, H = 64, NH = 16;
constexpr int BS = B * S;          // 8192 rows total
constexpr float SCALE = 0.125f;    // 1/sqrt(H)

// ---------------------------------------------------------------------------
// Wproj_eff[h][e] = sum_t Wproj[t*64+h][e]   (all 16 heads identical -> fold)
// ---------------------------------------------------------------------------
__global__ __launch_bounds__(256) void fold_wproj_kernel(const float* __restrict__ Wproj,
                                                         float* __restrict__ Wpe) {
    const int idx = blockIdx.x * 256 + threadIdx.x;   // 0..65535
    const int e = idx & (D - 1);
    const int h = idx >> 10;
    float s = 0.f;
#pragma unroll
    for (int t = 0; t < NH; ++t) s += Wproj[(t * H + h) * D + e];
    Wpe[h * D + e] = s;
}

// ---------------------------------------------------------------------------
// q/k/v = x @ W{q,k,v}, scalar-broadcast GEMM.
// Block = 256 thr (4 waves). Wave owns QKV_R rows x ALL 3 matrices.
// lane = output column h. x row data is wave-uniform -> scalar loads (SMEM
// pipe, no LDS, no VALU addr math); W loads coalesced 256B, L1/L2-resident.
// 12 FMA per x-float4. blockIdx.y = K-split (partials summed by reduce_add).
// ---------------------------------------------------------------------------
constexpr int QKV_R = 8;   // rows per wave

__global__ __launch_bounds__(256) void qkv2_kernel(const float* __restrict__ x,
                                                   const float* __restrict__ Wq,
                                                   const float* __restrict__ Wk,
                                                   const float* __restrict__ Wv,
                                                   float* __restrict__ outp,
                                                   int klen) {
    const int tid = threadIdx.x;
    const int h = tid & 63;
    const int wv = __builtin_amdgcn_readfirstlane(tid >> 6);
    const int row0 = blockIdx.x * (4 * QKV_R) + wv * QKV_R;
    const int k0base = blockIdx.y * klen;

    float acc[3][QKV_R];
#pragma unroll
    for (int m = 0; m < 3; ++m)
#pragma unroll
        for (int r = 0; r < QKV_R; ++r) acc[m][r] = 0.f;

    const float* __restrict__ xr = x + (size_t)row0 * D + k0base;

    for (int k0 = 0; k0 < klen; k0 += 4) {
        float wl[3][4];
#pragma unroll
        for (int j = 0; j < 4; ++j) {
            const size_t wi = (size_t)(k0base + k0 + j) * H + h;
            wl[0][j] = Wq[wi];
            wl[1][j] = Wk[wi];
            wl[2][j] = Wv[wi];
        }
#pragma unroll
        for (int r = 0; r < QKV_R; ++r) {
            const float4 xv = *reinterpret_cast<const float4*>(xr + (size_t)r * D + k0);  // uniform -> s_load
#pragma unroll
            for (int m = 0; m < 3; ++m) {
                acc[m][r] = fmaf(xv.x, wl[m][0], acc[m][r]);
                acc[m][r] = fmaf(xv.y, wl[m][1], acc[m][r]);
                acc[m][r] = fmaf(xv.z, wl[m][2], acc[m][r]);
                acc[m][r] = fmaf(xv.w, wl[m][3], acc[m][r]);
            }
        }
    }

    float* __restrict__ op = outp + (size_t)blockIdx.y * 3 * BS * H;
#pragma unroll
    for (int m = 0; m < 3; ++m)
#pragma unroll
        for (int r = 0; r < QKV_R; ++r)
            op[(size_t)m * BS * H + (size_t)(row0 + r) * H + h] = acc[m][r];
}

// a[i] += b[i], float4-wide (in-place split-K reduce)
__global__ __launch_bounds__(256) void reduce_add_kernel(float4* __restrict__ a,
                                                         const float4* __restrict__ b) {
    const int i = blockIdx.x * 256 + threadIdx.x;
    const float4 av = a[i], bv = b[i];
    a[i] = make_float4(av.x + bv.x, av.y + bv.y, av.z + bv.z, av.w + bv.w);
}

// ---------------------------------------------------------------------------
// Tile-parallel causal flash attention (unchanged from round 2).
// ---------------------------------------------------------------------------
constexpr int QB = 16;
constexpr int QW = 4;
constexpr int KT = 64;

__global__ __launch_bounds__(256) void attn_kernel(const float* __restrict__ q,
                                                   const float* __restrict__ k,
                                                   const float* __restrict__ v,
                                                   float* __restrict__ ctx) {
    __shared__ float ks[KT * H];       // swizzled k tile
    __shared__ float vs[KT * H];       // linear v tile
    __shared__ float qs[QB * H];       // scaled q rows
    __shared__ float ps[4][QW][KT];    // per-wave p scratch

    const int tid = threadIdx.x;
    const int lane = tid & 63;
    const int wave = tid >> 6;
    const int bid = blockIdx.x;
    const int b = bid & 3;
    const int q0 = (bid >> 2) * QB;

    const float* __restrict__ kb = k + b * S * H;
    const float* __restrict__ vb = v + b * S * H;

    {
        const float4* qg = reinterpret_cast<const float4*>(q + (b * S + q0) * H);
        float4 t = qg[tid];
        t.x *= SCALE; t.y *= SCALE; t.z *= SCALE; t.w *= SCALE;
        reinterpret_cast<float4*>(qs)[tid] = t;
    }

    float o[QW], l[QW], m[QW];
#pragma unroll
    for (int r = 0; r < QW; ++r) { o[r] = 0.f; l[r] = 0.f; m[r] = -1e30f; }

    const int qi_base = q0 + wave * QW;
    const int nt = (q0 + QB + KT - 1) / KT;

    for (int t = 0; t < nt; ++t) {
        const int kt0 = t * KT;
        __syncthreads();
        {
            const float4* kg = reinterpret_cast<const float4*>(kb + kt0 * H);
            const float4* vg = reinterpret_cast<const float4*>(vb + kt0 * H);
            float4* ks4 = reinterpret_cast<float4*>(ks);
            float4* vs4 = reinterpret_cast<float4*>(vs);
#pragma unroll
            for (int it = 0; it < 4; ++it) {
                const int i = tid + it * 256;
                const int j = i >> 4, c4 = i & 15;
                ks4[j * 16 + (c4 ^ (j & 7))] = kg[i];
                vs4[i] = vg[i];
            }
        }
        __syncthreads();

        float4 kr[16];
        {
            const float4* ks4 = reinterpret_cast<const float4*>(ks);
#pragma unroll
            for (int c4 = 0; c4 < 16; ++c4)
                kr[c4] = ks4[lane * 16 + (c4 ^ (lane & 7))];
        }
        const int kj = kt0 + lane;
        float s[QW];
#pragma unroll
        for (int rr = 0; rr < QW; ++rr) {
            const float4* q4 = reinterpret_cast<const float4*>(qs + (wave * QW + rr) * H);
            float acc = 0.f;
#pragma unroll
            for (int c4 = 0; c4 < 16; ++c4) {
                const float4 qv = q4[c4];
                acc = fmaf(qv.x, kr[c4].x, acc);
                acc = fmaf(qv.y, kr[c4].y, acc);
                acc = fmaf(qv.z, kr[c4].z, acc);
                acc = fmaf(qv.w, kr[c4].w, acc);
            }
            s[rr] = acc;
        }

#pragma unroll
        for (int rr = 0; rr < QW; ++rr) {
            const int qi = qi_base + rr;
            const float msk = (kj <= qi) ? 1.f : 0.f;
            float sv = (kj <= qi) ? s[rr] : -1e30f;
            float smax = sv;
#pragma unroll
            for (int off = 32; off > 0; off >>= 1)
                smax = fmaxf(smax, __shfl_xor(smax, off, 64));
            const float mn = fmaxf(m[rr], smax);
            const float p = __expf(sv - mn) * msk;
            float psum = p;
#pragma unroll
            for (int off = 32; off > 0; off >>= 1)
                psum += __shfl_xor(psum, off, 64);
            const float corr = __expf(m[rr] - mn);
            l[rr] = l[rr] * corr + psum;
            o[rr] *= corr;
            m[rr] = mn;
            ps[wave][rr][lane] = p;
        }

#pragma unroll 4
        for (int j4 = 0; j4 < 16; ++j4) {
            const float v0 = vs[(j4 * 4 + 0) * H + lane];
            const float v1 = vs[(j4 * 4 + 1) * H + lane];
            const float v2 = vs[(j4 * 4 + 2) * H + lane];
            const float v3 = vs[(j4 * 4 + 3) * H + lane];
#pragma unroll
            for (int rr = 0; rr < QW; ++rr) {
                const float4 pp = *reinterpret_cast<const float4*>(&ps[wave][rr][j4 * 4]);
                o[rr] = fmaf(pp.x, v0, o[rr]);
                o[rr] = fmaf(pp.y, v1, o[rr]);
                o[rr] = fmaf(pp.z, v2, o[rr]);
                o[rr] = fmaf(pp.w, v3, o[rr]);
            }
        }
    }

#pragma unroll
    for (int rr = 0; rr < QW; ++rr) {
        const int row = b * S + qi_base + rr;
        ctx[row * H + lane] = o[rr] / l[rr];
    }
}

// ---------------------------------------------------------------------------
// out = ctx @ Wproj_eff + bproj, scalar-broadcast version (no LDS).
// Thread owns column e; Wpe[:,e] in 64 VGPRs; ctx rows via uniform s_load.
// Grid: (D/256) x (BS/PROJ_RR).
// ---------------------------------------------------------------------------
constexpr int PROJ_RR = 32;

__global__ __launch_bounds__(256) void proj2_kernel(const float* __restrict__ ctx,
                                                    const float* __restrict__ Wpe,
                                                    const float* __restrict__ bias,
                                                    float* __restrict__ out) {
    const int tid = threadIdx.x;
    const int e = blockIdx.x * 256 + tid;
    const int row0 = blockIdx.y * PROJ_RR;

    float w[64];
#pragma unroll
    for (int hh = 0; hh < 64; ++hh) w[hh] = Wpe[hh * D + e];
    const float bb = bias[e];

    const float* __restrict__ cb = ctx + (size_t)row0 * H;
    for (int r = 0; r < PROJ_RR; ++r) {
        float acc = bb;
#pragma unroll
        for (int h4 = 0; h4 < 16; ++h4) {
            const float4 c = *reinterpret_cast<const float4*>(cb + r * H + h4 * 4);  // uniform -> s_load
            acc = fmaf(c.x, w[h4 * 4 + 0], acc);
            acc = fmaf(c.y, w[h4 * 4 + 1], acc);
            acc = fmaf(c.z, w[h4 * 4 + 2], acc);
            acc = fmaf(c.w, w[h4 * 4 + 3], acc);
        }
        out[(size_t)(row0 + r) * D + e] = acc;
    }
}

}  // namespace

extern "C" void kernel_launch(void* const* d_in, const int* in_sizes, int n_in,
                              void* d_out, int out_size, void* d_ws, size_t ws_size,
                              hipStream_t stream) {
    const float* x     = (const float*)d_in[0];
    const float* Wq    = (const float*)d_in[1];
    const float* Wk    = (const float*)d_in[2];
    const float* Wv    = (const float*)d_in[3];
    const float* Wproj = (const float*)d_in[4];
    const float* bproj = (const float*)d_in[5];
    float* out = (float*)d_out;

    float* ws = (float*)d_ws;
    // layout: [p0: 3*BS*H][p1: 3*BS*H (split-K only)][ctx: BS*H][Wpe: H*D]
    const size_t qkvN = (size_t)3 * BS * H;
    const size_t need2 = (2 * qkvN + (size_t)BS * H + (size_t)H * D) * sizeof(float);
    const int splitk = (ws_size >= need2) ? 2 : 1;

    float* p0  = ws;
    float* p1  = p0 + qkvN;
    float* ctx = (splitk == 2) ? (p1 + qkvN) : p1;
    float* Wpe = ctx + (size_t)BS * H;

    float* q = p0;
    float* k = p0 + (size_t)BS * H;
    float* v = p0 + (size_t)2 * BS * H;

    hipLaunchKernelGGL(fold_wproj_kernel, dim3((H * D) / 256), dim3(256), 0, stream, Wproj, Wpe);
    hipLaunchKernelGGL(qkv2_kernel, dim3(BS / (4 * QKV_R), splitk), dim3(256), 0, stream,
                       x, Wq, Wk, Wv, p0, D / splitk);
    if (splitk == 2)
        hipLaunchKernelGGL(reduce_add_kernel, dim3(qkvN / 4 / 256), dim3(256), 0, stream,
                           (float4*)p0, (const float4*)p1);
    hipLaunchKernelGGL(attn_kernel, dim3((S / QB) * B), dim3(256), 0, stream, q, k, v, ctx);
    hipLaunchKernelGGL(proj2_kernel, dim3(D / 256, BS / PROJ_RR), dim3(256), 0, stream, ctx, Wpe, bproj, out);
}

// Round 4
// 184.400 us; speedup vs baseline: 7.4117x; 1.5425x over previous
//
#include <hip/hip_runtime.h>
#include <hip/hip_bf16.h>
#include <math.h>

namespace {

constexpr int B = 4, S = 2048, D = 1024, H = 64, NH = 16;
constexpr int BS = B * S;                  // 8192 rows
constexpr float SCALE2 = 0.125f * 1.4426950408889634f;  // 1/sqrt(H) * log2(e): exp2 domain

using f32x4 = __attribute__((ext_vector_type(4))) float;
using short8b = __attribute__((ext_vector_type(8))) short;  // 8 bf16 (4 VGPRs)

__device__ inline ushort f2bf(float f) {
    __hip_bfloat16 h = __float2bfloat16(f);
    return *reinterpret_cast<ushort*>(&h);
}
__device__ inline float bf2f(ushort u) {
    __hip_bfloat16 h = *reinterpret_cast<__hip_bfloat16*>(&u);
    return __bfloat162float(h);
}

// ---------------------------------------------------------------------------
// Wproj_eff[h][e] = sum_t Wproj[t*64+h][e]
// ---------------------------------------------------------------------------
__global__ __launch_bounds__(256) void fold_wproj_kernel(const float* __restrict__ Wproj,
                                                         float* __restrict__ Wpe) {
    const int idx = blockIdx.x * 256 + threadIdx.x;
    const int e = idx & (D - 1);
    const int h = idx >> 10;
    float s = 0.f;
#pragma unroll
    for (int t = 0; t < NH; ++t) s += Wproj[(t * H + h) * D + e];
    Wpe[h * D + e] = s;
}

// ---------------------------------------------------------------------------
// q/k/v = x @ W{q,k,v}, scalar-broadcast GEMM (unchanged from round 3).
// ---------------------------------------------------------------------------
constexpr int QKV_R = 8;

__global__ __launch_bounds__(256) void qkv2_kernel(const float* __restrict__ x,
                                                   const float* __restrict__ Wq,
                                                   const float* __restrict__ Wk,
                                                   const float* __restrict__ Wv,
                                                   float* __restrict__ outp,
                                                   int klen) {
    const int tid = threadIdx.x;
    const int h = tid & 63;
    const int wv = __builtin_amdgcn_readfirstlane(tid >> 6);
    const int row0 = blockIdx.x * (4 * QKV_R) + wv * QKV_R;
    const int k0base = blockIdx.y * klen;

    float acc[3][QKV_R];
#pragma unroll
    for (int m = 0; m < 3; ++m)
#pragma unroll
        for (int r = 0; r < QKV_R; ++r) acc[m][r] = 0.f;

    const float* __restrict__ xr = x + (size_t)row0 * D + k0base;

    for (int k0 = 0; k0 < klen; k0 += 4) {
        float wl[3][4];
#pragma unroll
        for (int j = 0; j < 4; ++j) {
            const size_t wi = (size_t)(k0base + k0 + j) * H + h;
            wl[0][j] = Wq[wi];
            wl[1][j] = Wk[wi];
            wl[2][j] = Wv[wi];
        }
#pragma unroll
        for (int r = 0; r < QKV_R; ++r) {
            const float4 xv = *reinterpret_cast<const float4*>(xr + (size_t)r * D + k0);
#pragma unroll
            for (int m = 0; m < 3; ++m) {
                acc[m][r] = fmaf(xv.x, wl[m][0], acc[m][r]);
                acc[m][r] = fmaf(xv.y, wl[m][1], acc[m][r]);
                acc[m][r] = fmaf(xv.z, wl[m][2], acc[m][r]);
                acc[m][r] = fmaf(xv.w, wl[m][3], acc[m][r]);
            }
        }
    }

    float* __restrict__ op = outp + (size_t)blockIdx.y * 3 * BS * H;
#pragma unroll
    for (int m = 0; m < 3; ++m)
#pragma unroll
        for (int r = 0; r < QKV_R; ++r)
            op[(size_t)m * BS * H + (size_t)(row0 + r) * H + h] = acc[m][r];
}

__global__ __launch_bounds__(256) void reduce_add_kernel(float4* __restrict__ a,
                                                         const float4* __restrict__ b) {
    const int i = blockIdx.x * 256 + threadIdx.x;
    const float4 av = a[i], bv = b[i];
    a[i] = make_float4(av.x + bv.x, av.y + bv.y, av.z + bv.z, av.w + bv.w);
}

// ---------------------------------------------------------------------------
// Convert k,v (fp32, contiguous sections of p0) -> bf16 copies for attn.
// ---------------------------------------------------------------------------
__global__ __launch_bounds__(256) void cvt_kv_kernel(const float* __restrict__ src,
                                                     ushort* __restrict__ dst) {
    const int i = (blockIdx.x * 256 + threadIdx.x) * 8;
    const float4 a = *reinterpret_cast<const float4*>(src + i);
    const float4 b = *reinterpret_cast<const float4*>(src + i + 4);
    ushort u[8] = {f2bf(a.x), f2bf(a.y), f2bf(a.z), f2bf(a.w),
                   f2bf(b.x), f2bf(b.y), f2bf(b.z), f2bf(b.w)};
    *reinterpret_cast<int4*>(dst + i) = *reinterpret_cast<int4*>(u);
}

// ---------------------------------------------------------------------------
// MFMA causal flash attention, 1 wave per block, 16-row q-tile, KT=64 keys.
// Balanced KV-split: q-tile j (of 128/batch) has Tj=j/4+1 k-tiles split into
// nc=j/32+1 chunks. Units per batch = 320; grid = 1280. Partials (o,m,l) out.
// LDS: K tile [64][64] bf16 + V^T tile [64][64] bf16, both XOR-swizzled;
// P round-trip buffer [16][72] bf16.
// ---------------------------------------------------------------------------
__global__ __launch_bounds__(64) void attn_mfma_kernel(const float* __restrict__ q,
                                                       const ushort* __restrict__ kb16,
                                                       const ushort* __restrict__ vb16,
                                                       ushort* __restrict__ po,
                                                       float* __restrict__ pm,
                                                       float* __restrict__ pl) {
    __shared__ ushort ksm[64 * 64];
    __shared__ ushort vtm[64 * 64];
    __shared__ ushort plds[16 * 72];

    const int l = threadIdx.x;         // lane 0..63
    const int u = blockIdx.x;
    const int b = u & 3;
    const int ub = u >> 2;             // 0..319

    // unit -> (q-tile j, chunk c)
    int j, c;
    if (ub < 32)       { j = ub;                 c = 0; }
    else if (ub < 96)  { j = 32 + (ub - 32) / 2; c = (ub - 32) % 2; }
    else if (ub < 192) { j = 64 + (ub - 96) / 3; c = (ub - 96) % 3; }
    else               { j = 96 + (ub - 192) / 4; c = (ub - 192) % 4; }
    const int Tj = (j >> 2) + 1;
    const int nc = (j >> 5) + 1;
    const int len = (Tj + nc - 1) / nc;
    const int kt_begin = c * len;
    const int kt_end = min(kt_begin + len, Tj);

    const int lg = l >> 4;             // lane group 0..3
    const int li = l & 15;

    // ---- Q fragments (A-operand): row = li, k = lg*8 + [0..8) ----
    short8b aq0, aq1;
    {
        const float* qg = q + (size_t)(b * S + j * 16 + li) * H + lg * 8;
        const float4 f0 = *reinterpret_cast<const float4*>(qg);
        const float4 f1 = *reinterpret_cast<const float4*>(qg + 4);
        const float4 f2 = *reinterpret_cast<const float4*>(qg + 32);
        const float4 f3 = *reinterpret_cast<const float4*>(qg + 36);
        aq0[0] = f2bf(f0.x * SCALE2); aq0[1] = f2bf(f0.y * SCALE2);
        aq0[2] = f2bf(f0.z * SCALE2); aq0[3] = f2bf(f0.w * SCALE2);
        aq0[4] = f2bf(f1.x * SCALE2); aq0[5] = f2bf(f1.y * SCALE2);
        aq0[6] = f2bf(f1.z * SCALE2); aq0[7] = f2bf(f1.w * SCALE2);
        aq1[0] = f2bf(f2.x * SCALE2); aq1[1] = f2bf(f2.y * SCALE2);
        aq1[2] = f2bf(f2.z * SCALE2); aq1[3] = f2bf(f2.w * SCALE2);
        aq1[4] = f2bf(f3.x * SCALE2); aq1[5] = f2bf(f3.y * SCALE2);
        aq1[6] = f2bf(f3.z * SCALE2); aq1[7] = f2bf(f3.w * SCALE2);
    }

    f32x4 oacc[4];
#pragma unroll
    for (int t = 0; t < 4; ++t) oacc[t] = (f32x4){0.f, 0.f, 0.f, 0.f};
    float mrow[4] = {-1e30f, -1e30f, -1e30f, -1e30f};
    float lrow[4] = {0.f, 0.f, 0.f, 0.f};

    for (int kt = kt_begin; kt < kt_end; ++kt) {
        // ---- stage K tile: bf16 rows [key][64], swizzled ----
        {
            const ushort* kg = kb16 + (size_t)(b * S + kt * 64) * H;
#pragma unroll
            for (int it = 0; it < 8; ++it) {
                const int f = l + it * 64;       // 16B chunk id
                const int key = f >> 3, hd8 = f & 7;
                const int4 val = *reinterpret_cast<const int4*>(kg + key * 64 + hd8 * 8);
                int byteoff = (key << 7) + (hd8 << 4);
                byteoff ^= (key & 7) << 4;
                *reinterpret_cast<int4*>(reinterpret_cast<char*>(ksm) + byteoff) = val;
            }
        }
        // ---- stage V^T tile: [h][key] bf16, swizzled; transpose via v_perm ----
        {
            const ushort* vg = vb16 + (size_t)(b * S + kt * 64) * H;
#pragma unroll
            for (int it = 0; it < 4; ++it) {
                const int item = l + it * 64;    // 0..255
                const int kk = item >> 4;        // key quad
                const int hq = item & 15;        // h quad
                const uint2 a0 = *reinterpret_cast<const uint2*>(vg + (kk * 4 + 0) * 64 + hq * 4);
                const uint2 a1 = *reinterpret_cast<const uint2*>(vg + (kk * 4 + 1) * 64 + hq * 4);
                const uint2 a2 = *reinterpret_cast<const uint2*>(vg + (kk * 4 + 2) * 64 + hq * 4);
                const uint2 a3 = *reinterpret_cast<const uint2*>(vg + (kk * 4 + 3) * 64 + hq * 4);
#pragma unroll
                for (int i = 0; i < 4; ++i) {
                    const uint s0 = (i < 2) ? a0.x : a0.y;
                    const uint s1 = (i < 2) ? a1.x : a1.y;
                    const uint s2 = (i < 2) ? a2.x : a2.y;
                    const uint s3 = (i < 2) ? a3.x : a3.y;
                    const uint sel = (i & 1) ? 0x07060302u : 0x05040100u;
                    const uint w0 = __builtin_amdgcn_perm(s1, s0, sel);
                    const uint w1 = __builtin_amdgcn_perm(s3, s2, sel);
                    const int h = hq * 4 + i;
                    int byteoff = (h << 7) + (kk << 3);
                    byteoff ^= (h & 7) << 4;
                    *reinterpret_cast<uint2*>(reinterpret_cast<char*>(vtm) + byteoff) =
                        make_uint2(w0, w1);
                }
            }
        }
        __syncthreads();  // single wave: compiles to waitcnt only

        // ---- QK^T: 4 key-subtiles x 2 k-chunks ----
        f32x4 accs[4];
#pragma unroll
        for (int t = 0; t < 4; ++t) accs[t] = (f32x4){0.f, 0.f, 0.f, 0.f};
#pragma unroll
        for (int t = 0; t < 4; ++t) {
            const int key = t * 16 + li;
#pragma unroll
            for (int c2 = 0; c2 < 2; ++c2) {
                int byteoff = (key << 7) + (c2 << 6) + (lg << 4);
                byteoff ^= (key & 7) << 4;
                const short8b bk = *reinterpret_cast<const short8b*>(
                    reinterpret_cast<const char*>(ksm) + byteoff);
                accs[t] = __builtin_amdgcn_mfma_f32_16x16x32_bf16(
                    (c2 == 0) ? aq0 : aq1, bk, accs[t], 0, 0, 0);
            }
        }

        // ---- online softmax (exp2 domain) ----
        const bool straddle = (kt == (j >> 2));
        float sv[4][4];
#pragma unroll
        for (int t = 0; t < 4; ++t) {
            const int kg = kt * 64 + t * 16 + li;
#pragma unroll
            for (int r = 0; r < 4; ++r) {
                const int qrow = j * 16 + lg * 4 + r;
                sv[t][r] = (straddle && kg > qrow) ? -1e30f : accs[t][r];
            }
        }
        float pvals[4][4];
#pragma unroll
        for (int r = 0; r < 4; ++r) {
            float smax = fmaxf(fmaxf(sv[0][r], sv[1][r]), fmaxf(sv[2][r], sv[3][r]));
#pragma unroll
            for (int off = 1; off < 16; off <<= 1)
                smax = fmaxf(smax, __shfl_xor(smax, off, 64));
            const float mn = fmaxf(mrow[r], smax);
            const float corr = exp2f(mrow[r] - mn);
            mrow[r] = mn;
            float rsum = 0.f;
#pragma unroll
            for (int t = 0; t < 4; ++t) {
                pvals[t][r] = exp2f(sv[t][r] - mn);
                rsum += pvals[t][r];
            }
#pragma unroll
            for (int off = 1; off < 16; off <<= 1)
                rsum += __shfl_xor(rsum, off, 64);
            lrow[r] = lrow[r] * corr + rsum;
#pragma unroll
            for (int t = 0; t < 4; ++t) oacc[t][r] *= corr;
        }

        // ---- P -> LDS (bf16, C-layout write, A-layout read) ----
#pragma unroll
        for (int t = 0; t < 4; ++t)
#pragma unroll
            for (int r = 0; r < 4; ++r)
                plds[(lg * 4 + r) * 72 + t * 16 + li] = f2bf(pvals[t][r]);
        __syncthreads();

        // ---- PV: A = P frags, B = V^T tiles ----
        short8b ap0 = *reinterpret_cast<const short8b*>(
            reinterpret_cast<const char*>(plds) + li * 144 + (lg << 4));
        short8b ap1 = *reinterpret_cast<const short8b*>(
            reinterpret_cast<const char*>(plds) + li * 144 + 64 + (lg << 4));
#pragma unroll
        for (int t = 0; t < 4; ++t) {
            const int h = t * 16 + li;
#pragma unroll
            for (int c2 = 0; c2 < 2; ++c2) {
                int byteoff = (h << 7) + (c2 << 6) + (lg << 4);
                byteoff ^= (h & 7) << 4;
                const short8b bv = *reinterpret_cast<const short8b*>(
                    reinterpret_cast<const char*>(vtm) + byteoff);
                oacc[t] = __builtin_amdgcn_mfma_f32_16x16x32_bf16(
                    (c2 == 0) ? ap0 : ap1, bv, oacc[t], 0, 0, 0);
            }
        }
        __syncthreads();
    }

    // ---- write partials ----
    if (li == 0) {
#pragma unroll
        for (int r = 0; r < 4; ++r) {
            pm[u * 16 + lg * 4 + r] = mrow[r];
            pl[u * 16 + lg * 4 + r] = lrow[r];
        }
    }
#pragma unroll
    for (int t = 0; t < 4; ++t)
#pragma unroll
        for (int r = 0; r < 4; ++r)
            po[(size_t)u * 1024 + (lg * 4 + r) * 64 + t * 16 + li] = f2bf(oacc[t][r]);
}

// ---------------------------------------------------------------------------
// Combine KV-split partials -> ctx. One block (64 thr) per 16-row q-tile.
// ---------------------------------------------------------------------------
__global__ __launch_bounds__(64) void combine_kernel(const ushort* __restrict__ po,
                                                     const float* __restrict__ pm,
                                                     const float* __restrict__ pl,
                                                     float* __restrict__ ctx) {
    const int bid = blockIdx.x;
    const int b = bid & 3;
    const int j = bid >> 2;
    const int h = threadIdx.x;
    const int nc = (j >> 5) + 1;
    const int cum = (j < 32) ? j
                  : (j < 64) ? 32 + 2 * (j - 32)
                  : (j < 96) ? 96 + 3 * (j - 64)
                  : 192 + 4 * (j - 96);

    for (int qr = 0; qr < 16; ++qr) {
        float M = -1e30f;
        for (int c = 0; c < nc; ++c) {
            const int uu = 4 * (cum + c) + b;
            M = fmaxf(M, pm[uu * 16 + qr]);
        }
        float denom = 0.f, acc = 0.f;
        for (int c = 0; c < nc; ++c) {
            const int uu = 4 * (cum + c) + b;
            const float sc = exp2f(pm[uu * 16 + qr] - M);
            denom += pl[uu * 16 + qr] * sc;
            acc += bf2f(po[(size_t)uu * 1024 + qr * 64 + h]) * sc;
        }
        ctx[(size_t)(b * S + j * 16 + qr) * H + h] = acc / denom;
    }
}

// ---------------------------------------------------------------------------
// out = ctx @ Wproj_eff + bproj (unchanged from round 3).
// ---------------------------------------------------------------------------
constexpr int PROJ_RR = 32;

__global__ __launch_bounds__(256) void proj2_kernel(const float* __restrict__ ctx,
                                                    const float* __restrict__ Wpe,
                                                    const float* __restrict__ bias,
                                                    float* __restrict__ out) {
    const int tid = threadIdx.x;
    const int e = blockIdx.x * 256 + tid;
    const int row0 = blockIdx.y * PROJ_RR;

    float w[64];
#pragma unroll
    for (int hh = 0; hh < 64; ++hh) w[hh] = Wpe[hh * D + e];
    const float bb = bias[e];

    const float* __restrict__ cb = ctx + (size_t)row0 * H;
    for (int r = 0; r < PROJ_RR; ++r) {
        float acc = bb;
#pragma unroll
        for (int h4 = 0; h4 < 16; ++h4) {
            const float4 c = *reinterpret_cast<const float4*>(cb + r * H + h4 * 4);
            acc = fmaf(c.x, w[h4 * 4 + 0], acc);
            acc = fmaf(c.y, w[h4 * 4 + 1], acc);
            acc = fmaf(c.z, w[h4 * 4 + 2], acc);
            acc = fmaf(c.w, w[h4 * 4 + 3], acc);
        }
        out[(size_t)(row0 + r) * D + e] = acc;
    }
}

}  // namespace

extern "C" void kernel_launch(void* const* d_in, const int* in_sizes, int n_in,
                              void* d_out, int out_size, void* d_ws, size_t ws_size,
                              hipStream_t stream) {
    const float* x     = (const float*)d_in[0];
    const float* Wq    = (const float*)d_in[1];
    const float* Wk    = (const float*)d_in[2];
    const float* Wv    = (const float*)d_in[3];
    const float* Wproj = (const float*)d_in[4];
    const float* bproj = (const float*)d_in[5];
    float* out = (float*)d_out;

    float* ws = (float*)d_ws;
    const size_t BSH = (size_t)BS * H;          // 524288
    const size_t qkvN = 3 * BSH;
    // [p0: qkv fp32][p1: splitk partial, then attn partials][ctxkv: bf16 k/v then ctx][Wpe]
    const size_t need2 = (2 * qkvN + BSH + (size_t)H * D) * sizeof(float);
    const int splitk = (ws_size >= need2) ? 2 : 1;

    float* p0    = ws;
    float* p1    = p0 + qkvN;
    float* ctxkv = (splitk == 2) ? (p1 + qkvN) : p1;
    float* Wpe   = ctxkv + BSH;

    float* q = p0;
    ushort* kv16 = (ushort*)ctxkv;              // kb16 | vb16 (2*BSH ushorts = BSH floats)
    ushort* kb16 = kv16;
    ushort* vb16 = kv16 + BSH;
    float* ctx = ctxkv;                         // reused after attn is done with kv16

    // attn partials live in (dead-after-cvt) p1: po bf16 + pm/pl f32
    ushort* po = (ushort*)((splitk == 2) ? p1 : (ctxkv + BSH + (size_t)H * D));
    float* pm = (float*)(po + (size_t)1280 * 1024);
    float* pl = pm + 1280 * 16;

    hipLaunchKernelGGL(fold_wproj_kernel, dim3((H * D) / 256), dim3(256), 0, stream, Wproj, Wpe);
    hipLaunchKernelGGL(qkv2_kernel, dim3(BS / (4 * QKV_R), splitk), dim3(256), 0, stream,
                       x, Wq, Wk, Wv, p0, D / splitk);
    if (splitk == 2)
        hipLaunchKernelGGL(reduce_add_kernel, dim3(qkvN / 4 / 256), dim3(256), 0, stream,
                           (float4*)p0, (const float4*)p1);
    hipLaunchKernelGGL(cvt_kv_kernel, dim3((2 * BSH) / (256 * 8)), dim3(256), 0, stream,
                       p0 + BSH, kv16);
    hipLaunchKernelGGL(attn_mfma_kernel, dim3(1280), dim3(64), 0, stream,
                       q, kb16, vb16, po, pm, pl);
    hipLaunchKernelGGL(combine_kernel, dim3(512), dim3(64), 0, stream, po, pm, pl, ctx);
    hipLaunchKernelGGL(proj2_kernel, dim3(D / 256, BS / PROJ_RR), dim3(256), 0, stream,
                       ctx, Wpe, bproj, out);
}

// Round 5
// 135.542 us; speedup vs baseline: 10.0833x; 1.3605x over previous
//
#include <hip/hip_runtime.h>
#include <hip/hip_bf16.h>
#include <math.h>

namespace {

constexpr int B = 4, S = 2048, D = 1024, H = 64, NH = 16;
constexpr int BS = B * S;                  // 8192 rows
constexpr float SCALE2 = 0.125f * 1.4426950408889634f;  // 1/sqrt(H) * log2(e): exp2 domain

using f32x4 = __attribute__((ext_vector_type(4))) float;
using short8b = __attribute__((ext_vector_type(8))) short;  // 8 bf16 (4 VGPRs)

__device__ inline ushort f2bf(float f) {
    __hip_bfloat16 h = __float2bfloat16(f);
    return *reinterpret_cast<ushort*>(&h);
}
__device__ inline float bf2f(ushort u) {
    __hip_bfloat16 h = *reinterpret_cast<__hip_bfloat16*>(&u);
    return __bfloat162float(h);
}

// ---------------------------------------------------------------------------
// Wproj_eff[h][e] = sum_t Wproj[t*64+h][e]
// ---------------------------------------------------------------------------
__global__ __launch_bounds__(256) void fold_wproj_kernel(const float* __restrict__ Wproj,
                                                         float* __restrict__ Wpe) {
    const int idx = blockIdx.x * 256 + threadIdx.x;
    const int e = idx & (D - 1);
    const int h = idx >> 10;
    float s = 0.f;
#pragma unroll
    for (int t = 0; t < NH; ++t) s += Wproj[(t * H + h) * D + e];
    Wpe[h * D + e] = s;
}

// ---------------------------------------------------------------------------
// Wt[n][k] (bf16, n in 0..191 = Wq|Wk|Wv columns) = W[k][n&63].
// Writes coalesced (consecutive tid = consecutive k).
// ---------------------------------------------------------------------------
__global__ __launch_bounds__(256) void cvt_wt_kernel(const float* __restrict__ Wq,
                                                     const float* __restrict__ Wk,
                                                     const float* __restrict__ Wv,
                                                     ushort* __restrict__ Wt) {
    const int idx = blockIdx.x * 256 + threadIdx.x;   // 0..196607
    const int n = idx >> 10, k = idx & 1023;
    const float* __restrict__ W = (n < 64) ? Wq : (n < 128) ? Wk : Wv;
    Wt[idx] = f2bf(W[k * 64 + (n & 63)]);
}

// ---------------------------------------------------------------------------
// qkv via MFMA: [8192 x 1024] x [1024 x 192] -> q,k,v bf16 (q pre-scaled).
// Block = 256 thr (4 waves: 2M x 2N). M-tile 32 rows, K-step 64.
// LDS: xs [32][64] bf16 (cvt in staging), wsm [192][64] bf16 (W^T rows);
// both XOR-swizzled (byte ^= (row&7)<<4) -> conflict-free ds_read_b128.
// ---------------------------------------------------------------------------
__global__ __launch_bounds__(256) void qkv3_kernel(const float* __restrict__ x,
                                                   const ushort* __restrict__ Wt,
                                                   ushort* __restrict__ qb,
                                                   ushort* __restrict__ kb,
                                                   ushort* __restrict__ vb) {
    __shared__ ushort xs[32 * 64];
    __shared__ ushort wsm[192 * 64];
    const int tid = threadIdx.x;
    const int lane = tid & 63;
    const int li = lane & 15, lg = lane >> 4;
    const int wave = tid >> 6;
    const int wm = wave >> 1, wn = wave & 1;
    const int row0 = blockIdx.x * 32;

    f32x4 acc[6];
#pragma unroll
    for (int t = 0; t < 6; ++t) acc[t] = (f32x4){0.f, 0.f, 0.f, 0.f};

    const int srow = tid >> 3, skc = tid & 7;   // x staging coords

    for (int k0 = 0; k0 < 1024; k0 += 64) {
        __syncthreads();
        // stage x (fp32 -> bf16), swizzled
        {
            const float* xp = x + (size_t)(row0 + srow) * 1024 + k0 + skc * 8;
            const float4 f0 = *reinterpret_cast<const float4*>(xp);
            const float4 f1 = *reinterpret_cast<const float4*>(xp + 4);
            ushort u[8] = {f2bf(f0.x), f2bf(f0.y), f2bf(f0.z), f2bf(f0.w),
                           f2bf(f1.x), f2bf(f1.y), f2bf(f1.z), f2bf(f1.w)};
            int boff = srow * 128 + skc * 16;
            boff ^= (srow & 7) << 4;
            *reinterpret_cast<int4*>(reinterpret_cast<char*>(xs) + boff) =
                *reinterpret_cast<int4*>(u);
        }
        // stage W^T tile rows (bf16 already), swizzled
#pragma unroll
        for (int it = 0; it < 6; ++it) {
            const int cid = tid + it * 256;
            const int n = cid >> 3, kc = cid & 7;
            const int4 val = *reinterpret_cast<const int4*>(Wt + (size_t)n * 1024 + k0 + kc * 8);
            int boff = n * 128 + kc * 16;
            boff ^= (n & 7) << 4;
            *reinterpret_cast<int4*>(reinterpret_cast<char*>(wsm) + boff) = val;
        }
        __syncthreads();

        // A fragments (wave's 16 rows, two k-chunks of 32)
        const int arow = wm * 16 + li;
        int aoff = arow * 128 + lg * 16;
        aoff ^= (arow & 7) << 4;
        const short8b a0 = *reinterpret_cast<const short8b*>(
            reinterpret_cast<const char*>(xs) + aoff);
        const short8b a1 = *reinterpret_cast<const short8b*>(
            reinterpret_cast<const char*>(xs) + (aoff ^ 64));

#pragma unroll
        for (int t = 0; t < 6; ++t) {
            const int n = wn * 96 + t * 16 + li;
            int boff = n * 128 + lg * 16;
            boff ^= (n & 7) << 4;
            const short8b b0 = *reinterpret_cast<const short8b*>(
                reinterpret_cast<const char*>(wsm) + boff);
            const short8b b1 = *reinterpret_cast<const short8b*>(
                reinterpret_cast<const char*>(wsm) + (boff ^ 64));
            acc[t] = __builtin_amdgcn_mfma_f32_16x16x32_bf16(a0, b0, acc[t], 0, 0, 0);
            acc[t] = __builtin_amdgcn_mfma_f32_16x16x32_bf16(a1, b1, acc[t], 0, 0, 0);
        }
    }

    // epilogue: C[row][col], col = li (m89 layout); q scaled into exp2 domain
#pragma unroll
    for (int t = 0; t < 6; ++t) {
        const int col = wn * 96 + t * 16 + li;
        const int m = col >> 6, cc = col & 63;
        ushort* __restrict__ dst = (m == 0) ? qb : (m == 1) ? kb : vb;
        const float sc = (m == 0) ? SCALE2 : 1.f;
#pragma unroll
        for (int r = 0; r < 4; ++r) {
            const int gr = row0 + wm * 16 + lg * 4 + r;
            dst[(size_t)gr * 64 + cc] = f2bf(acc[t][r] * sc);
        }
    }
}

// ---------------------------------------------------------------------------
// MFMA causal flash attention, 1 wave per block, 16-row q-tile, KT=64 keys.
// Balanced KV-split: q-tile j (of 128/batch) has Tj=j/4+1 k-tiles split into
// nc=j/32+1 chunks. Units per batch = 320; grid = 1280. Partials (o,m,l) out.
// Q now arrives bf16 pre-scaled -> plain int4 fragment loads.
// ---------------------------------------------------------------------------
__global__ __launch_bounds__(64) void attn_mfma_kernel(const ushort* __restrict__ qb,
                                                       const ushort* __restrict__ kb16,
                                                       const ushort* __restrict__ vb16,
                                                       ushort* __restrict__ po,
                                                       float* __restrict__ pm,
                                                       float* __restrict__ pl) {
    __shared__ ushort ksm[64 * 64];
    __shared__ ushort vtm[64 * 64];
    __shared__ ushort plds[16 * 72];

    const int l = threadIdx.x;         // lane 0..63
    const int u = blockIdx.x;
    const int b = u & 3;
    const int ub = u >> 2;             // 0..319

    int j, c;
    if (ub < 32)       { j = ub;                 c = 0; }
    else if (ub < 96)  { j = 32 + (ub - 32) / 2; c = (ub - 32) % 2; }
    else if (ub < 192) { j = 64 + (ub - 96) / 3; c = (ub - 96) % 3; }
    else               { j = 96 + (ub - 192) / 4; c = (ub - 192) % 4; }
    const int Tj = (j >> 2) + 1;
    const int nc = (j >> 5) + 1;
    const int len = (Tj + nc - 1) / nc;
    const int kt_begin = c * len;
    const int kt_end = min(kt_begin + len, Tj);

    const int lg = l >> 4;
    const int li = l & 15;

    // Q fragments: row = li, k = lg*8 + [0..8) and +32
    const ushort* qg = qb + (size_t)(b * S + j * 16 + li) * H + lg * 8;
    const short8b aq0 = *reinterpret_cast<const short8b*>(qg);
    const short8b aq1 = *reinterpret_cast<const short8b*>(qg + 32);

    f32x4 oacc[4];
#pragma unroll
    for (int t = 0; t < 4; ++t) oacc[t] = (f32x4){0.f, 0.f, 0.f, 0.f};
    float mrow[4] = {-1e30f, -1e30f, -1e30f, -1e30f};
    float lrow[4] = {0.f, 0.f, 0.f, 0.f};

    for (int kt = kt_begin; kt < kt_end; ++kt) {
        // stage K tile: bf16 rows [key][64], swizzled
        {
            const ushort* kg = kb16 + (size_t)(b * S + kt * 64) * H;
#pragma unroll
            for (int it = 0; it < 8; ++it) {
                const int f = l + it * 64;
                const int key = f >> 3, hd8 = f & 7;
                const int4 val = *reinterpret_cast<const int4*>(kg + key * 64 + hd8 * 8);
                int byteoff = (key << 7) + (hd8 << 4);
                byteoff ^= (key & 7) << 4;
                *reinterpret_cast<int4*>(reinterpret_cast<char*>(ksm) + byteoff) = val;
            }
        }
        // stage V^T tile: [h][key] bf16, swizzled; transpose via v_perm
        {
            const ushort* vg = vb16 + (size_t)(b * S + kt * 64) * H;
#pragma unroll
            for (int it = 0; it < 4; ++it) {
                const int item = l + it * 64;
                const int kk = item >> 4;
                const int hq = item & 15;
                const uint2 a0 = *reinterpret_cast<const uint2*>(vg + (kk * 4 + 0) * 64 + hq * 4);
                const uint2 a1 = *reinterpret_cast<const uint2*>(vg + (kk * 4 + 1) * 64 + hq * 4);
                const uint2 a2 = *reinterpret_cast<const uint2*>(vg + (kk * 4 + 2) * 64 + hq * 4);
                const uint2 a3 = *reinterpret_cast<const uint2*>(vg + (kk * 4 + 3) * 64 + hq * 4);
#pragma unroll
                for (int i = 0; i < 4; ++i) {
                    const uint s0 = (i < 2) ? a0.x : a0.y;
                    const uint s1 = (i < 2) ? a1.x : a1.y;
                    const uint s2 = (i < 2) ? a2.x : a2.y;
                    const uint s3 = (i < 2) ? a3.x : a3.y;
                    const uint sel = (i & 1) ? 0x07060302u : 0x05040100u;
                    const uint w0 = __builtin_amdgcn_perm(s1, s0, sel);
                    const uint w1 = __builtin_amdgcn_perm(s3, s2, sel);
                    const int h = hq * 4 + i;
                    int byteoff = (h << 7) + (kk << 3);
                    byteoff ^= (h & 7) << 4;
                    *reinterpret_cast<uint2*>(reinterpret_cast<char*>(vtm) + byteoff) =
                        make_uint2(w0, w1);
                }
            }
        }
        __syncthreads();

        // QK^T
        f32x4 accs[4];
#pragma unroll
        for (int t = 0; t < 4; ++t) accs[t] = (f32x4){0.f, 0.f, 0.f, 0.f};
#pragma unroll
        for (int t = 0; t < 4; ++t) {
            const int key = t * 16 + li;
#pragma unroll
            for (int c2 = 0; c2 < 2; ++c2) {
                int byteoff = (key << 7) + (c2 << 6) + (lg << 4);
                byteoff ^= (key & 7) << 4;
                const short8b bk = *reinterpret_cast<const short8b*>(
                    reinterpret_cast<const char*>(ksm) + byteoff);
                accs[t] = __builtin_amdgcn_mfma_f32_16x16x32_bf16(
                    (c2 == 0) ? aq0 : aq1, bk, accs[t], 0, 0, 0);
            }
        }

        // online softmax (exp2 domain)
        const bool straddle = (kt == (j >> 2));
        float sv[4][4];
#pragma unroll
        for (int t = 0; t < 4; ++t) {
            const int kg = kt * 64 + t * 16 + li;
#pragma unroll
            for (int r = 0; r < 4; ++r) {
                const int qrow = j * 16 + lg * 4 + r;
                sv[t][r] = (straddle && kg > qrow) ? -1e30f : accs[t][r];
            }
        }
        float pvals[4][4];
#pragma unroll
        for (int r = 0; r < 4; ++r) {
            float smax = fmaxf(fmaxf(sv[0][r], sv[1][r]), fmaxf(sv[2][r], sv[3][r]));
#pragma unroll
            for (int off = 1; off < 16; off <<= 1)
                smax = fmaxf(smax, __shfl_xor(smax, off, 64));
            const float mn = fmaxf(mrow[r], smax);
            const float corr = exp2f(mrow[r] - mn);
            mrow[r] = mn;
            float rsum = 0.f;
#pragma unroll
            for (int t = 0; t < 4; ++t) {
                pvals[t][r] = exp2f(sv[t][r] - mn);
                rsum += pvals[t][r];
            }
#pragma unroll
            for (int off = 1; off < 16; off <<= 1)
                rsum += __shfl_xor(rsum, off, 64);
            lrow[r] = lrow[r] * corr + rsum;
#pragma unroll
            for (int t = 0; t < 4; ++t) oacc[t][r] *= corr;
        }

        // P -> LDS (bf16)
#pragma unroll
        for (int t = 0; t < 4; ++t)
#pragma unroll
            for (int r = 0; r < 4; ++r)
                plds[(lg * 4 + r) * 72 + t * 16 + li] = f2bf(pvals[t][r]);
        __syncthreads();

        // PV
        short8b ap0 = *reinterpret_cast<const short8b*>(
            reinterpret_cast<const char*>(plds) + li * 144 + (lg << 4));
        short8b ap1 = *reinterpret_cast<const short8b*>(
            reinterpret_cast<const char*>(plds) + li * 144 + 64 + (lg << 4));
#pragma unroll
        for (int t = 0; t < 4; ++t) {
            const int h = t * 16 + li;
#pragma unroll
            for (int c2 = 0; c2 < 2; ++c2) {
                int byteoff = (h << 7) + (c2 << 6) + (lg << 4);
                byteoff ^= (h & 7) << 4;
                const short8b bv = *reinterpret_cast<const short8b*>(
                    reinterpret_cast<const char*>(vtm) + byteoff);
                oacc[t] = __builtin_amdgcn_mfma_f32_16x16x32_bf16(
                    (c2 == 0) ? ap0 : ap1, bv, oacc[t], 0, 0, 0);
            }
        }
        __syncthreads();
    }

    // write partials
    if (li == 0) {
#pragma unroll
        for (int r = 0; r < 4; ++r) {
            pm[u * 16 + lg * 4 + r] = mrow[r];
            pl[u * 16 + lg * 4 + r] = lrow[r];
        }
    }
#pragma unroll
    for (int t = 0; t < 4; ++t)
#pragma unroll
        for (int r = 0; r < 4; ++r)
            po[(size_t)u * 1024 + (lg * 4 + r) * 64 + t * 16 + li] = f2bf(oacc[t][r]);
}

// ---------------------------------------------------------------------------
// Combine KV-split partials -> ctx. One block (64 thr) per 16-row q-tile.
// ---------------------------------------------------------------------------
__global__ __launch_bounds__(64) void combine_kernel(const ushort* __restrict__ po,
                                                     const float* __restrict__ pm,
                                                     const float* __restrict__ pl,
                                                     float* __restrict__ ctx) {
    const int bid = blockIdx.x;
    const int b = bid & 3;
    const int j = bid >> 2;
    const int h = threadIdx.x;
    const int nc = (j >> 5) + 1;
    const int cum = (j < 32) ? j
                  : (j < 64) ? 32 + 2 * (j - 32)
                  : (j < 96) ? 96 + 3 * (j - 64)
                  : 192 + 4 * (j - 96);

    for (int qr = 0; qr < 16; ++qr) {
        float M = -1e30f;
        for (int c = 0; c < nc; ++c) {
            const int uu = 4 * (cum + c) + b;
            M = fmaxf(M, pm[uu * 16 + qr]);
        }
        float denom = 0.f, acc = 0.f;
        for (int c = 0; c < nc; ++c) {
            const int uu = 4 * (cum + c) + b;
            const float sc = exp2f(pm[uu * 16 + qr] - M);
            denom += pl[uu * 16 + qr] * sc;
            acc += bf2f(po[(size_t)uu * 1024 + qr * 64 + h]) * sc;
        }
        ctx[(size_t)(b * S + j * 16 + qr) * H + h] = acc / denom;
    }
}

// ---------------------------------------------------------------------------
// out = ctx @ Wproj_eff + bproj.
// ---------------------------------------------------------------------------
constexpr int PROJ_RR = 32;

__global__ __launch_bounds__(256) void proj2_kernel(const float* __restrict__ ctx,
                                                    const float* __restrict__ Wpe,
                                                    const float* __restrict__ bias,
                                                    float* __restrict__ out) {
    const int tid = threadIdx.x;
    const int e = blockIdx.x * 256 + tid;
    const int row0 = blockIdx.y * PROJ_RR;

    float w[64];
#pragma unroll
    for (int hh = 0; hh < 64; ++hh) w[hh] = Wpe[hh * D + e];
    const float bb = bias[e];

    const float* __restrict__ cb = ctx + (size_t)row0 * H;
    for (int r = 0; r < PROJ_RR; ++r) {
        float acc = bb;
#pragma unroll
        for (int h4 = 0; h4 < 16; ++h4) {
            const float4 c = *reinterpret_cast<const float4*>(cb + r * H + h4 * 4);
            acc = fmaf(c.x, w[h4 * 4 + 0], acc);
            acc = fmaf(c.y, w[h4 * 4 + 1], acc);
            acc = fmaf(c.z, w[h4 * 4 + 2], acc);
            acc = fmaf(c.w, w[h4 * 4 + 3], acc);
        }
        out[(size_t)(row0 + r) * D + e] = acc;
    }
}

}  // namespace

extern "C" void kernel_launch(void* const* d_in, const int* in_sizes, int n_in,
                              void* d_out, int out_size, void* d_ws, size_t ws_size,
                              hipStream_t stream) {
    const float* x     = (const float*)d_in[0];
    const float* Wq    = (const float*)d_in[1];
    const float* Wk    = (const float*)d_in[2];
    const float* Wv    = (const float*)d_in[3];
    const float* Wproj = (const float*)d_in[4];
    const float* bproj = (const float*)d_in[5];
    float* out = (float*)d_out;

    const size_t BSH = (size_t)BS * H;          // 524288
    // ws layout (bytes): qb 1MB | kb 1MB | vb 1MB | Wt 384KB | ctx 2MB | Wpe 256KB
    //                    | po 2.5MB | pm 80KB | pl 80KB   (total ~8.3 MB)
    ushort* qb  = (ushort*)d_ws;
    ushort* kb  = qb + BSH;
    ushort* vb  = kb + BSH;
    ushort* Wt  = vb + BSH;                     // 192*1024
    float*  ctx = (float*)(Wt + 192 * 1024);
    float*  Wpe = ctx + BSH;
    ushort* po  = (ushort*)(Wpe + (size_t)H * D);
    float*  pm  = (float*)(po + (size_t)1280 * 1024);
    float*  pl  = pm + 1280 * 16;

    hipLaunchKernelGGL(fold_wproj_kernel, dim3((H * D) / 256), dim3(256), 0, stream, Wproj, Wpe);
    hipLaunchKernelGGL(cvt_wt_kernel, dim3(192 * 1024 / 256), dim3(256), 0, stream, Wq, Wk, Wv, Wt);
    hipLaunchKernelGGL(qkv3_kernel, dim3(BS / 32), dim3(256), 0, stream, x, Wt, qb, kb, vb);
    hipLaunchKernelGGL(attn_mfma_kernel, dim3(1280), dim3(64), 0, stream,
                       qb, kb, vb, po, pm, pl);
    hipLaunchKernelGGL(combine_kernel, dim3(512), dim3(64), 0, stream, po, pm, pl, ctx);
    hipLaunchKernelGGL(proj2_kernel, dim3(D / 256, BS / PROJ_RR), dim3(256), 0, stream,
                       ctx, Wpe, bproj, out);
}

// Round 6
// 70.092 us; speedup vs baseline: 19.4989x; 1.9338x over previous
//
#include <hip/hip_runtime.h>
#include <hip/hip_bf16.h>
#include <math.h>

namespace {

constexpr int B = 4, S = 2048, D = 1024, H = 64, NH = 16;
constexpr int BS = B * S;                  // 8192 rows
constexpr float SCALE2 = 0.125f * 1.4426950408889634f;  // 1/sqrt(H) * log2(e): exp2 domain

using f32x4 = __attribute__((ext_vector_type(4))) float;
using short8b = __attribute__((ext_vector_type(8))) short;  // 8 bf16 (4 VGPRs)

__device__ inline ushort f2bf(float f) {
    __hip_bfloat16 h = __float2bfloat16(f);
    return *reinterpret_cast<ushort*>(&h);
}
__device__ inline float bf2f(ushort u) {
    __hip_bfloat16 h = *reinterpret_cast<__hip_bfloat16*>(&u);
    return __bfloat162float(h);
}

// ---------------------------------------------------------------------------
// prep: [bid<768]  Wt[n][k] bf16 = W{q,k,v}[k][n&63]   (QKV B-operand)
//       [bid>=768] Wpet[e][h] bf16 = sum_t Wproj[t*64+h][e]  (proj B-operand)
// ---------------------------------------------------------------------------
__global__ __launch_bounds__(256) void prep_kernel(const float* __restrict__ Wq,
                                                   const float* __restrict__ Wk,
                                                   const float* __restrict__ Wv,
                                                   const float* __restrict__ Wproj,
                                                   ushort* __restrict__ Wt,
                                                   ushort* __restrict__ Wpet) {
    const int bid = blockIdx.x;
    const int tid = threadIdx.x;
    if (bid < 768) {
        const int idx = bid * 256 + tid;          // 0..196607
        const int n = idx >> 10, k = idx & 1023;
        const float* __restrict__ W = (n < 64) ? Wq : (n < 128) ? Wk : Wv;
        Wt[idx] = f2bf(W[k * 64 + (n & 63)]);
    } else {
        const int idx = (bid - 768) * 256 + tid;  // 0..65535
        const int e = idx & 1023, h = idx >> 10;
        float s = 0.f;
#pragma unroll
        for (int t = 0; t < NH; ++t) s += Wproj[(t * H + h) * D + e];
        Wpet[e * 64 + h] = f2bf(s);
    }
}

// ---------------------------------------------------------------------------
// qkv via MFMA: [8192 x 1024] x [1024 x 192] -> q,k,v bf16 (q pre-scaled).
// Block = 256 thr (4 waves: 2M x 2N). M-tile 32 rows, K-step 64.
// LDS: xs [32][64] bf16, wsm [192][64] bf16; XOR-swizzled (byte ^= (row&7)<<4).
// ---------------------------------------------------------------------------
__global__ __launch_bounds__(256) void qkv3_kernel(const float* __restrict__ x,
                                                   const ushort* __restrict__ Wt,
                                                   ushort* __restrict__ qb,
                                                   ushort* __restrict__ kb,
                                                   ushort* __restrict__ vb) {
    __shared__ ushort xs[32 * 64];
    __shared__ ushort wsm[192 * 64];
    const int tid = threadIdx.x;
    const int lane = tid & 63;
    const int li = lane & 15, lg = lane >> 4;
    const int wave = tid >> 6;
    const int wm = wave >> 1, wn = wave & 1;
    const int row0 = blockIdx.x * 32;

    f32x4 acc[6];
#pragma unroll
    for (int t = 0; t < 6; ++t) acc[t] = (f32x4){0.f, 0.f, 0.f, 0.f};

    const int srow = tid >> 3, skc = tid & 7;   // x staging coords

    for (int k0 = 0; k0 < 1024; k0 += 64) {
        __syncthreads();
        // stage x (fp32 -> bf16), swizzled
        {
            const float* xp = x + (size_t)(row0 + srow) * 1024 + k0 + skc * 8;
            const float4 f0 = *reinterpret_cast<const float4*>(xp);
            const float4 f1 = *reinterpret_cast<const float4*>(xp + 4);
            ushort u[8] = {f2bf(f0.x), f2bf(f0.y), f2bf(f0.z), f2bf(f0.w),
                           f2bf(f1.x), f2bf(f1.y), f2bf(f1.z), f2bf(f1.w)};
            int boff = srow * 128 + skc * 16;
            boff ^= (srow & 7) << 4;
            *reinterpret_cast<int4*>(reinterpret_cast<char*>(xs) + boff) =
                *reinterpret_cast<int4*>(u);
        }
        // stage W^T tile rows (bf16 already), swizzled
#pragma unroll
        for (int it = 0; it < 6; ++it) {
            const int cid = tid + it * 256;
            const int n = cid >> 3, kc = cid & 7;
            const int4 val = *reinterpret_cast<const int4*>(Wt + (size_t)n * 1024 + k0 + kc * 8);
            int boff = n * 128 + kc * 16;
            boff ^= (n & 7) << 4;
            *reinterpret_cast<int4*>(reinterpret_cast<char*>(wsm) + boff) = val;
        }
        __syncthreads();

        // A fragments (wave's 16 rows, two k-chunks of 32)
        const int arow = wm * 16 + li;
        int aoff = arow * 128 + lg * 16;
        aoff ^= (arow & 7) << 4;
        const short8b a0 = *reinterpret_cast<const short8b*>(
            reinterpret_cast<const char*>(xs) + aoff);
        const short8b a1 = *reinterpret_cast<const short8b*>(
            reinterpret_cast<const char*>(xs) + (aoff ^ 64));

#pragma unroll
        for (int t = 0; t < 6; ++t) {
            const int n = wn * 96 + t * 16 + li;
            int boff = n * 128 + lg * 16;
            boff ^= (n & 7) << 4;
            const short8b b0 = *reinterpret_cast<const short8b*>(
                reinterpret_cast<const char*>(wsm) + boff);
            const short8b b1 = *reinterpret_cast<const short8b*>(
                reinterpret_cast<const char*>(wsm) + (boff ^ 64));
            acc[t] = __builtin_amdgcn_mfma_f32_16x16x32_bf16(a0, b0, acc[t], 0, 0, 0);
            acc[t] = __builtin_amdgcn_mfma_f32_16x16x32_bf16(a1, b1, acc[t], 0, 0, 0);
        }
    }

    // epilogue: C[row][col], col = li (m89 layout); q scaled into exp2 domain
#pragma unroll
    for (int t = 0; t < 6; ++t) {
        const int col = wn * 96 + t * 16 + li;
        const int m = col >> 6, cc = col & 63;
        ushort* __restrict__ dst = (m == 0) ? qb : (m == 1) ? kb : vb;
        const float sc = (m == 0) ? SCALE2 : 1.f;
#pragma unroll
        for (int r = 0; r < 4; ++r) {
            const int gr = row0 + wm * 16 + lg * 4 + r;
            dst[(size_t)gr * 64 + cc] = f2bf(acc[t][r] * sc);
        }
    }
}

// ---------------------------------------------------------------------------
// MFMA causal flash attention, 1 wave per block, 16-row q-tile, KT=64 keys.
// Balanced KV-split: q-tile j has Tj=j/4+1 k-tiles split into nc=j/32+1
// chunks. Units/batch = 320; grid = 1280. Partials (o bf16, m, l) out.
// ---------------------------------------------------------------------------
__global__ __launch_bounds__(64) void attn_mfma_kernel(const ushort* __restrict__ qb,
                                                       const ushort* __restrict__ kb16,
                                                       const ushort* __restrict__ vb16,
                                                       ushort* __restrict__ po,
                                                       float* __restrict__ pm,
                                                       float* __restrict__ pl) {
    __shared__ ushort ksm[64 * 64];
    __shared__ ushort vtm[64 * 64];
    __shared__ ushort plds[16 * 72];

    const int l = threadIdx.x;         // lane 0..63
    const int u = blockIdx.x;
    const int b = u & 3;
    const int ub = u >> 2;             // 0..319

    int j, c;
    if (ub < 32)       { j = ub;                 c = 0; }
    else if (ub < 96)  { j = 32 + (ub - 32) / 2; c = (ub - 32) % 2; }
    else if (ub < 192) { j = 64 + (ub - 96) / 3; c = (ub - 96) % 3; }
    else               { j = 96 + (ub - 192) / 4; c = (ub - 192) % 4; }
    const int Tj = (j >> 2) + 1;
    const int nc = (j >> 5) + 1;
    const int len = (Tj + nc - 1) / nc;
    const int kt_begin = c * len;
    const int kt_end = min(kt_begin + len, Tj);

    const int lg = l >> 4;
    const int li = l & 15;

    // Q fragments: row = li, k = lg*8 + [0..8) and +32
    const ushort* qg = qb + (size_t)(b * S + j * 16 + li) * H + lg * 8;
    const short8b aq0 = *reinterpret_cast<const short8b*>(qg);
    const short8b aq1 = *reinterpret_cast<const short8b*>(qg + 32);

    f32x4 oacc[4];
#pragma unroll
    for (int t = 0; t < 4; ++t) oacc[t] = (f32x4){0.f, 0.f, 0.f, 0.f};
    float mrow[4] = {-1e30f, -1e30f, -1e30f, -1e30f};
    float lrow[4] = {0.f, 0.f, 0.f, 0.f};

    for (int kt = kt_begin; kt < kt_end; ++kt) {
        // stage K tile: bf16 rows [key][64], swizzled
        {
            const ushort* kg = kb16 + (size_t)(b * S + kt * 64) * H;
#pragma unroll
            for (int it = 0; it < 8; ++it) {
                const int f = l + it * 64;
                const int key = f >> 3, hd8 = f & 7;
                const int4 val = *reinterpret_cast<const int4*>(kg + key * 64 + hd8 * 8);
                int byteoff = (key << 7) + (hd8 << 4);
                byteoff ^= (key & 7) << 4;
                *reinterpret_cast<int4*>(reinterpret_cast<char*>(ksm) + byteoff) = val;
            }
        }
        // stage V^T tile: [h][key] bf16, swizzled; transpose via v_perm
        {
            const ushort* vg = vb16 + (size_t)(b * S + kt * 64) * H;
#pragma unroll
            for (int it = 0; it < 4; ++it) {
                const int item = l + it * 64;
                const int kk = item >> 4;
                const int hq = item & 15;
                const uint2 a0 = *reinterpret_cast<const uint2*>(vg + (kk * 4 + 0) * 64 + hq * 4);
                const uint2 a1 = *reinterpret_cast<const uint2*>(vg + (kk * 4 + 1) * 64 + hq * 4);
                const uint2 a2 = *reinterpret_cast<const uint2*>(vg + (kk * 4 + 2) * 64 + hq * 4);
                const uint2 a3 = *reinterpret_cast<const uint2*>(vg + (kk * 4 + 3) * 64 + hq * 4);
#pragma unroll
                for (int i = 0; i < 4; ++i) {
                    const uint s0 = (i < 2) ? a0.x : a0.y;
                    const uint s1 = (i < 2) ? a1.x : a1.y;
                    const uint s2 = (i < 2) ? a2.x : a2.y;
                    const uint s3 = (i < 2) ? a3.x : a3.y;
                    const uint sel = (i & 1) ? 0x07060302u : 0x05040100u;
                    const uint w0 = __builtin_amdgcn_perm(s1, s0, sel);
                    const uint w1 = __builtin_amdgcn_perm(s3, s2, sel);
                    const int h = hq * 4 + i;
                    int byteoff = (h << 7) + (kk << 3);
                    byteoff ^= (h & 7) << 4;
                    *reinterpret_cast<uint2*>(reinterpret_cast<char*>(vtm) + byteoff) =
                        make_uint2(w0, w1);
                }
            }
        }
        __syncthreads();

        // QK^T
        f32x4 accs[4];
#pragma unroll
        for (int t = 0; t < 4; ++t) accs[t] = (f32x4){0.f, 0.f, 0.f, 0.f};
#pragma unroll
        for (int t = 0; t < 4; ++t) {
            const int key = t * 16 + li;
#pragma unroll
            for (int c2 = 0; c2 < 2; ++c2) {
                int byteoff = (key << 7) + (c2 << 6) + (lg << 4);
                byteoff ^= (key & 7) << 4;
                const short8b bk = *reinterpret_cast<const short8b*>(
                    reinterpret_cast<const char*>(ksm) + byteoff);
                accs[t] = __builtin_amdgcn_mfma_f32_16x16x32_bf16(
                    (c2 == 0) ? aq0 : aq1, bk, accs[t], 0, 0, 0);
            }
        }

        // online softmax (exp2 domain)
        const bool straddle = (kt == (j >> 2));
        float sv[4][4];
#pragma unroll
        for (int t = 0; t < 4; ++t) {
            const int kg = kt * 64 + t * 16 + li;
#pragma unroll
            for (int r = 0; r < 4; ++r) {
                const int qrow = j * 16 + lg * 4 + r;
                sv[t][r] = (straddle && kg > qrow) ? -1e30f : accs[t][r];
            }
        }
        float pvals[4][4];
#pragma unroll
        for (int r = 0; r < 4; ++r) {
            float smax = fmaxf(fmaxf(sv[0][r], sv[1][r]), fmaxf(sv[2][r], sv[3][r]));
#pragma unroll
            for (int off = 1; off < 16; off <<= 1)
                smax = fmaxf(smax, __shfl_xor(smax, off, 64));
            const float mn = fmaxf(mrow[r], smax);
            const float corr = exp2f(mrow[r] - mn);
            mrow[r] = mn;
            float rsum = 0.f;
#pragma unroll
            for (int t = 0; t < 4; ++t) {
                pvals[t][r] = exp2f(sv[t][r] - mn);
                rsum += pvals[t][r];
            }
#pragma unroll
            for (int off = 1; off < 16; off <<= 1)
                rsum += __shfl_xor(rsum, off, 64);
            lrow[r] = lrow[r] * corr + rsum;
#pragma unroll
            for (int t = 0; t < 4; ++t) oacc[t][r] *= corr;
        }

        // P -> LDS (bf16)
#pragma unroll
        for (int t = 0; t < 4; ++t)
#pragma unroll
            for (int r = 0; r < 4; ++r)
                plds[(lg * 4 + r) * 72 + t * 16 + li] = f2bf(pvals[t][r]);
        __syncthreads();

        // PV
        short8b ap0 = *reinterpret_cast<const short8b*>(
            reinterpret_cast<const char*>(plds) + li * 144 + (lg << 4));
        short8b ap1 = *reinterpret_cast<const short8b*>(
            reinterpret_cast<const char*>(plds) + li * 144 + 64 + (lg << 4));
#pragma unroll
        for (int t = 0; t < 4; ++t) {
            const int h = t * 16 + li;
#pragma unroll
            for (int c2 = 0; c2 < 2; ++c2) {
                int byteoff = (h << 7) + (c2 << 6) + (lg << 4);
                byteoff ^= (h & 7) << 4;
                const short8b bv = *reinterpret_cast<const short8b*>(
                    reinterpret_cast<const char*>(vtm) + byteoff);
                oacc[t] = __builtin_amdgcn_mfma_f32_16x16x32_bf16(
                    (c2 == 0) ? ap0 : ap1, bv, oacc[t], 0, 0, 0);
            }
        }
        __syncthreads();
    }

    // write partials
    if (li == 0) {
#pragma unroll
        for (int r = 0; r < 4; ++r) {
            pm[u * 16 + lg * 4 + r] = mrow[r];
            pl[u * 16 + lg * 4 + r] = lrow[r];
        }
    }
#pragma unroll
    for (int t = 0; t < 4; ++t)
#pragma unroll
        for (int r = 0; r < 4; ++r)
            po[(size_t)u * 1024 + (lg * 4 + r) * 64 + t * 16 + li] = f2bf(oacc[t][r]);
}

// ---------------------------------------------------------------------------
// Fused combine + projection.  Block (256 thr) per 16-row q-tile (512 blocks).
// Phase 1: merge KV-split partials -> bf16 ctx tile in swizzled LDS.
// Phase 2: out[16][1024] = ctx[16][64] @ Wpet[64][1024] + bias via MFMA;
//          wave w covers cols w*256..w*256+255 (16 N-tiles, 2 MFMA each).
// ---------------------------------------------------------------------------
__global__ __launch_bounds__(256) void proj_fused_kernel(const ushort* __restrict__ po,
                                                         const float* __restrict__ pm,
                                                         const float* __restrict__ pl,
                                                         const ushort* __restrict__ Wpet,
                                                         const float* __restrict__ bias,
                                                         float* __restrict__ out) {
    __shared__ ushort ctxs[16 * 64];
    const int tid = threadIdx.x;
    const int bid = blockIdx.x;            // 0..511
    const int b = bid >> 7, j = bid & 127;
    const int nc = (j >> 5) + 1;
    const int cum = (j < 32) ? j
                  : (j < 64) ? 32 + 2 * (j - 32)
                  : (j < 96) ? 96 + 3 * (j - 64)
                  : 192 + 4 * (j - 96);

    // ---- phase 1: combine partials; thread -> (row qr, 4 h's) ----
    {
        const int qr = tid >> 4, hq = tid & 15;
        float M = -1e30f;
        for (int c = 0; c < nc; ++c) {
            const int uu = 4 * (cum + c) + b;
            M = fmaxf(M, pm[uu * 16 + qr]);
        }
        float denom = 0.f;
        float acc[4] = {0.f, 0.f, 0.f, 0.f};
        for (int c = 0; c < nc; ++c) {
            const int uu = 4 * (cum + c) + b;
            const float sc = exp2f(pm[uu * 16 + qr] - M);
            denom += pl[uu * 16 + qr] * sc;
            const ushort* pp = po + (size_t)uu * 1024 + qr * 64 + hq * 4;
            acc[0] += bf2f(pp[0]) * sc;
            acc[1] += bf2f(pp[1]) * sc;
            acc[2] += bf2f(pp[2]) * sc;
            acc[3] += bf2f(pp[3]) * sc;
        }
        const float inv = 1.f / denom;
        ushort u[4] = {f2bf(acc[0] * inv), f2bf(acc[1] * inv),
                       f2bf(acc[2] * inv), f2bf(acc[3] * inv)};
        int boff = qr * 128 + hq * 8;
        boff ^= (qr & 7) << 4;
        *reinterpret_cast<uint2*>(reinterpret_cast<char*>(ctxs) + boff) =
            *reinterpret_cast<uint2*>(u);
    }
    __syncthreads();

    // ---- phase 2: MFMA projection ----
    const int lane = tid & 63;
    const int li = lane & 15, lg = lane >> 4;
    const int wave = tid >> 6;
    const int col0 = wave * 256;
    const int row0 = bid * 16;

    int aoff = li * 128 + lg * 16;
    aoff ^= (li & 7) << 4;
    const short8b a0 = *reinterpret_cast<const short8b*>(
        reinterpret_cast<const char*>(ctxs) + aoff);
    const short8b a1 = *reinterpret_cast<const short8b*>(
        reinterpret_cast<const char*>(ctxs) + (aoff ^ 64));

#pragma unroll
    for (int t = 0; t < 16; ++t) {
        const int col = col0 + t * 16 + li;
        const ushort* bg = Wpet + (size_t)col * 64 + lg * 8;
        const short8b b0 = *reinterpret_cast<const short8b*>(bg);
        const short8b b1 = *reinterpret_cast<const short8b*>(bg + 32);
        f32x4 acc = (f32x4){0.f, 0.f, 0.f, 0.f};
        acc = __builtin_amdgcn_mfma_f32_16x16x32_bf16(a0, b0, acc, 0, 0, 0);
        acc = __builtin_amdgcn_mfma_f32_16x16x32_bf16(a1, b1, acc, 0, 0, 0);
        const float bb = bias[col];
#pragma unroll
        for (int r = 0; r < 4; ++r)
            out[(size_t)(row0 + lg * 4 + r) * 1024 + col] = acc[r] + bb;
    }
}

}  // namespace

extern "C" void kernel_launch(void* const* d_in, const int* in_sizes, int n_in,
                              void* d_out, int out_size, void* d_ws, size_t ws_size,
                              hipStream_t stream) {
    const float* x     = (const float*)d_in[0];
    const float* Wq    = (const float*)d_in[1];
    const float* Wk    = (const float*)d_in[2];
    const float* Wv    = (const float*)d_in[3];
    const float* Wproj = (const float*)d_in[4];
    const float* bproj = (const float*)d_in[5];
    float* out = (float*)d_out;

    const size_t BSH = (size_t)BS * H;          // 524288
    // ws layout: qb 1MB | kb 1MB | vb 1MB | Wt 384KB | Wpet 128KB
    //            | po 2.5MB | pm 80KB | pl 80KB   (~6.2 MB)
    ushort* qb   = (ushort*)d_ws;
    ushort* kb   = qb + BSH;
    ushort* vb   = kb + BSH;
    ushort* Wt   = vb + BSH;                    // 192*1024
    ushort* Wpet = Wt + 192 * 1024;             // 1024*64
    ushort* po   = Wpet + 65536;
    float*  pm   = (float*)(po + (size_t)1280 * 1024);
    float*  pl   = pm + 1280 * 16;

    hipLaunchKernelGGL(prep_kernel, dim3(1024), dim3(256), 0, stream, Wq, Wk, Wv, Wproj, Wt, Wpet);
    hipLaunchKernelGGL(qkv3_kernel, dim3(BS / 32), dim3(256), 0, stream, x, Wt, qb, kb, vb);
    hipLaunchKernelGGL(attn_mfma_kernel, dim3(1280), dim3(64), 0, stream,
                       qb, kb, vb, po, pm, pl);
    hipLaunchKernelGGL(proj_fused_kernel, dim3(512), dim3(256), 0, stream,
                       po, pm, pl, Wpet, bproj, out);
}